// Round 13
// baseline (177.779 us; speedup 1.0000x reference)
//
#include <hip/hip_runtime.h>
#include <stdint.h>

#define NFRAMES 2
#define NT 4           // NTYPES
#define BLK 256        // pair-kernel block size (4 waves)
#define NJ 64          // j-chunks: nloc/NJ = 64 atoms per tile
#define JT 64          // j-tile size (= nloc/NJ)
#define IPT 2          // atoms per thread in pair kernel
#define FBLK 64        // finalize block size (1 wave)
#define RPAIR 12       // probe: pair hot-loop repeats
#define RFIN 63        // probe: finalize load-loop repeats

typedef float f32x2 __attribute__((ext_vector_type(2)));

// ---------------------------------------------------------------------------
// 2 pairs via packed VOP3P f32 math (inline asm); i-coords pre-negated.
// ---------------------------------------------------------------------------
__device__ __forceinline__ f32x2 pk_r2(f32x2 jx, f32x2 jy, f32x2 jz,
                                       f32x2 nx, f32x2 ny, f32x2 nz) {
    f32x2 dx, dy, dz, t1, t2, r2;
    asm("v_pk_add_f32 %0, %1, %2" : "=v"(dx) : "v"(jx), "v"(nx));
    asm("v_pk_add_f32 %0, %1, %2" : "=v"(dy) : "v"(jy), "v"(ny));
    asm("v_pk_add_f32 %0, %1, %2" : "=v"(dz) : "v"(jz), "v"(nz));
    asm("v_pk_mul_f32 %0, %1, %1" : "=v"(t1) : "v"(dz));
    asm("v_pk_fma_f32 %0, %1, %1, %2" : "=v"(t2) : "v"(dy), "v"(t1));
    asm("v_pk_fma_f32 %0, %1, %1, %2" : "=v"(r2) : "v"(dx), "v"(t2));
    return r2;
}

template <bool SELFCHK>
__device__ __forceinline__ void tile_loop(const float4* __restrict__ A,
                                          const float4* __restrict__ B,
                                          int jbase,
                                          const int (&ii)[IPT],
                                          const f32x2 (&nX)[IPT],
                                          const f32x2 (&nY)[IPT],
                                          const f32x2 (&nZ)[IPT],
                                          float (&mm)[IPT],
                                          unsigned (&cA)[IPT], unsigned (&cB)[IPT]) {
#pragma unroll 8
    for (int h = 0; h < JT / 2; ++h) {
        const float4 a = A[h];                    // {x0,x1,y0,y1}
        const float4 b = B[h];                    // {z0,z1,s0bits,s1bits}
        const f32x2 jx = {a.x, a.y};
        const f32x2 jy = {a.z, a.w};
        const f32x2 jz = {b.x, b.y};
        const unsigned s0 = __float_as_uint(b.z);
        const unsigned s1 = __float_as_uint(b.w);
        const int j0 = jbase + 2 * h;
#pragma unroll
        for (int k = 0; k < IPT; ++k) {
            f32x2 r2 = pk_r2(jx, jy, jz, nX[k], nY[k], nZ[k]);
            float lo = r2.x, hi = r2.y;
            if (SELFCHK) {
                lo = (j0     == ii[k]) ? __builtin_inff() : lo;
                hi = (j0 + 1 == ii[k]) ? __builtin_inff() : hi;
            }
            mm[k] = fminf(mm[k], fminf(lo, hi));  // v_min3
            cA[k] += (lo < 36.0f) ? s0 : 0u;
            cB[k] += (hi < 36.0f) ? s1 : 0u;
        }
    }
}

// ---------------------------------------------------------------------------
// shared prologue helper: stage tile + set up per-thread atoms
// ---------------------------------------------------------------------------
__device__ __forceinline__ bool pair_setup(const float* __restrict__ cf,
                                           const int* __restrict__ tf,
                                           int jbase, int ib, int q,
                                           float4* A, float4* B,
                                           int (&ii)[IPT],
                                           f32x2 (&nX)[IPT], f32x2 (&nY)[IPT], f32x2 (&nZ)[IPT],
                                           float (&mm)[IPT],
                                           unsigned (&cA)[IPT], unsigned (&cB)[IPT]) {
    if (threadIdx.x < JT / 2) {
        const int j0 = jbase + 2 * threadIdx.x;
        A[threadIdx.x] = make_float4(cf[3 * j0], cf[3 * j0 + 3],
                                     cf[3 * j0 + 1], cf[3 * j0 + 4]);
        B[threadIdx.x] = make_float4(cf[3 * j0 + 2], cf[3 * j0 + 5],
                                     __uint_as_float(1u << (tf[j0] * 8)),
                                     __uint_as_float(1u << (tf[j0 + 1] * 8)));
    }
    __syncthreads();
    bool ov = false;
#pragma unroll
    for (int k = 0; k < IPT; ++k) {
        const int base = ib + k * q;
        ii[k] = base + threadIdx.x;
        const float nx = -cf[3 * ii[k]];
        const float ny = -cf[3 * ii[k] + 1];
        const float nz = -cf[3 * ii[k] + 2];
        nX[k] = (f32x2){nx, nx};
        nY[k] = (f32x2){ny, ny};
        nZ[k] = (f32x2){nz, nz};
        mm[k] = __builtin_inff();
        cA[k] = cB[k] = 0u;
        ov |= (jbase >= base) && (jbase < base + BLK);
    }
    return ov;
}

// ---------------------------------------------------------------------------
// REAL pair kernel (identical behavior to R12)
// ---------------------------------------------------------------------------
__global__ __launch_bounds__(BLK) void ns_pair_kernel(const float* __restrict__ coord,
                                                      const int* __restrict__ atype,
                                                      uint2* __restrict__ part,
                                                      float* __restrict__ out,
                                                      int nloc) {
    const int f = blockIdx.z;
    const int q = nloc / IPT;
    const int ib = blockIdx.y * BLK;
    const int jbase = blockIdx.x * JT;

    if (blockIdx.x == 0 && blockIdx.y == 0 && f == 0 && threadIdx.x < NFRAMES * NT)
        ((unsigned*)out)[(size_t)NFRAMES * nloc + threadIdx.x] = 0u;

    const float* cf = coord + (size_t)f * nloc * 3;
    const int*   tf = atype + (size_t)f * nloc;

    __shared__ float4 A[JT / 2], B[JT / 2];
    int ii[IPT];
    f32x2 nX[IPT], nY[IPT], nZ[IPT];
    float mm[IPT];
    unsigned cA[IPT], cB[IPT];
    const bool ov = pair_setup(cf, tf, jbase, ib, q, A, B, ii, nX, nY, nZ, mm, cA, cB);

    if (ov)
        tile_loop<true >(A, B, jbase, ii, nX, nY, nZ, mm, cA, cB);
    else
        tile_loop<false>(A, B, jbase, ii, nX, nY, nZ, mm, cA, cB);

    const size_t pb = ((size_t)blockIdx.x * NFRAMES + f) * nloc;
#pragma unroll
    for (int k = 0; k < IPT; ++k)
        part[pb + ii[k]] = make_uint2(__float_as_uint(mm[k]), cA[k] + cB[k]);
}

// ---------------------------------------------------------------------------
// REAL finalize (identical to R12)
// ---------------------------------------------------------------------------
__global__ __launch_bounds__(FBLK) void ns_finalize_kernel(const uint2* __restrict__ part,
                                                           float* __restrict__ out,
                                                           int nloc) {
    const int nbpf = nloc / FBLK;
    const int f = blockIdx.x / nbpf;
    const int i = (blockIdx.x % nbpf) * FBLK + threadIdx.x;

    float ma = __builtin_inff(), mb = __builtin_inff();
    unsigned cacc = 0u, cbacc = 0u;
#pragma unroll 16
    for (int jb = 0; jb < NJ; jb += 2) {
        uint2 va = part[((size_t)jb * NFRAMES + f) * nloc + i];
        uint2 vb = part[((size_t)(jb + 1) * NFRAMES + f) * nloc + i];
        ma = fminf(ma, __uint_as_float(va.x));
        mb = fminf(mb, __uint_as_float(vb.x));
        cacc += va.y;
        cbacc += vb.y;
    }
    out[(size_t)f * nloc + i] = fminf(ma, mb);
    const unsigned c = cacc + cbacc;

    int m0 = (int)(c & 255u);
    int m1 = (int)((c >> 8) & 255u);
    int m2 = (int)((c >> 16) & 255u);
    int m3 = (int)(c >> 24);
    for (int off = 32; off > 0; off >>= 1) {
        m0 = max(m0, __shfl_xor(m0, off, 64));
        m1 = max(m1, __shfl_xor(m1, off, 64));
        m2 = max(m2, __shfl_xor(m2, off, 64));
        m3 = max(m3, __shfl_xor(m3, off, 64));
    }
    if (threadIdx.x < NT) {
        const int t = threadIdx.x;
        const int mv = (t == 0) ? m0 : (t == 1) ? m1 : (t == 2) ? m2 : m3;
        atomicMax((unsigned*)out + (size_t)NFRAMES * nloc + f * NT + t,
                  __float_as_uint((float)mv));
    }
}

// ---------------------------------------------------------------------------
// PROBE pair: hot loop x RPAIR (reps 1.. into asm-sunk shadow accumulators);
// writes to scratch part2, never touches out.
// ---------------------------------------------------------------------------
__global__ __launch_bounds__(BLK) void ns_pair_probe(const float* __restrict__ coord,
                                                     const int* __restrict__ atype,
                                                     uint2* __restrict__ part2,
                                                     int nloc) {
    const int f = blockIdx.z;
    const int q = nloc / IPT;
    const int ib = blockIdx.y * BLK;
    const int jbase = blockIdx.x * JT;

    const float* cf = coord + (size_t)f * nloc * 3;
    const int*   tf = atype + (size_t)f * nloc;

    __shared__ float4 A[JT / 2], B[JT / 2];
    int ii[IPT];
    f32x2 nX[IPT], nY[IPT], nZ[IPT];
    float mm[IPT], mS[IPT];
    unsigned cA[IPT], cB[IPT], cS[IPT], cT[IPT];
    const bool ov = pair_setup(cf, tf, jbase, ib, q, A, B, ii, nX, nY, nZ, mm, cA, cB);
#pragma unroll
    for (int k = 0; k < IPT; ++k) { mS[k] = __builtin_inff(); cS[k] = cT[k] = 0u; }

    if (ov) {
        tile_loop<true >(A, B, jbase, ii, nX, nY, nZ, mm, cA, cB);
#pragma unroll 1
        for (int rep = 1; rep < RPAIR; ++rep)
            tile_loop<true >(A, B, jbase, ii, nX, nY, nZ, mS, cS, cT);
    } else {
        tile_loop<false>(A, B, jbase, ii, nX, nY, nZ, mm, cA, cB);
#pragma unroll 1
        for (int rep = 1; rep < RPAIR; ++rep)
            tile_loop<false>(A, B, jbase, ii, nX, nY, nZ, mS, cS, cT);
    }

#pragma unroll
    for (int k = 0; k < IPT; ++k)
        asm volatile("" :: "v"(mS[k]), "v"(cS[k]), "v"(cT[k]));

    const size_t pb = ((size_t)blockIdx.x * NFRAMES + f) * nloc;
#pragma unroll
    for (int k = 0; k < IPT; ++k)
        part2[pb + ii[k]] = make_uint2(__float_as_uint(mm[k]), cA[k] + cB[k]);
}

// ---------------------------------------------------------------------------
// PROBE finalize: load-reduce loop x RFIN with data-dependent rotation
// (accumulator-chained across reps -> no cross-rep load elimination).
// Reads scratch part2, writes scratch sink; never touches out.
// ---------------------------------------------------------------------------
__global__ __launch_bounds__(FBLK) void ns_fin_probe(const uint2* __restrict__ part2,
                                                     float* __restrict__ sink,
                                                     int nloc) {
    const int nbpf = nloc / FBLK;
    const int f = blockIdx.x / nbpf;
    const int i = (blockIdx.x % nbpf) * FBLK + threadIdx.x;

    float ma = __builtin_inff(), mb = __builtin_inff();
    unsigned cacc = 0u, cbacc = 0u;
#pragma unroll 1
    for (int rep = 0; rep < RFIN; ++rep) {
        const int rot = (int)(cacc & 1u);          // cross-rep data dependency
#pragma unroll 16
        for (int jb = 0; jb < NJ; jb += 2) {
            uint2 va = part2[((size_t)((jb + rot) & (NJ - 1)) * NFRAMES + f) * nloc + i];
            uint2 vb = part2[((size_t)((jb + 1 + rot) & (NJ - 1)) * NFRAMES + f) * nloc + i];
            ma = fminf(ma, __uint_as_float(va.x));
            mb = fminf(mb, __uint_as_float(vb.x));
            cacc += va.y;
            cbacc += vb.y;
        }
    }
    sink[(size_t)f * nloc + i] = fminf(ma, mb) + (float)(cacc + cbacc);
}

extern "C" void kernel_launch(void* const* d_in, const int* in_sizes, int n_in,
                              void* d_out, int out_size, void* d_ws, size_t ws_size,
                              hipStream_t stream) {
    const float* coord = (const float*)d_in[0];
    const int*   atype = (const int*)d_in[1];
    const int nloc = in_sizes[1] / NFRAMES;

    float* out   = (float*)d_out;
    uint2* part  = (uint2*)d_ws;                               // 4 MB @ 0
    uint2* part2 = (uint2*)((char*)d_ws + (8u << 20));         // 4 MB @ 8 MB (scratch)
    float* sink  = (float*)((char*)d_ws + (16u << 20));        // 32 KB @ 16 MB (scratch)

    dim3 grid(NJ, nloc / (BLK * IPT), NFRAMES);
    ns_pair_kernel<<<grid, dim3(BLK), 0, stream>>>(coord, atype, part, out, nloc);

    const int nbpf = nloc / FBLK;
    ns_finalize_kernel<<<NFRAMES * nbpf, FBLK, 0, stream>>>(part, out, nloc);

    // ---- diagnostic probes (scratch only; real output already written) ----
    ns_pair_probe<<<grid, dim3(BLK), 0, stream>>>(coord, atype, part2, nloc);
    ns_fin_probe<<<NFRAMES * nbpf, FBLK, 0, stream>>>(part2, sink, nloc);
}

// Round 14
// 30.267 us; speedup vs baseline: 5.8737x; 5.8737x over previous
//
#include <hip/hip_runtime.h>
#include <stdint.h>

#define NFRAMES 2
#define NT 4           // NTYPES
#define BLK 256        // pair-kernel block size (4 waves)
#define NJ 128         // j-chunks: nloc/NJ = 32 atoms per tile
#define JT 32          // j-tile size
#define IPT 4          // atoms per thread (each LDS read feeds 8 pairs)
#define FBLK 64        // finalize block size (1 wave)

typedef float f32x2 __attribute__((ext_vector_type(2)));

// ---------------------------------------------------------------------------
// 2 pairs via packed VOP3P f32 math (inline asm); i-coords pre-negated.
// ---------------------------------------------------------------------------
__device__ __forceinline__ f32x2 pk_r2(f32x2 jx, f32x2 jy, f32x2 jz,
                                       f32x2 nx, f32x2 ny, f32x2 nz) {
    f32x2 dx, dy, dz, t1, t2, r2;
    asm("v_pk_add_f32 %0, %1, %2" : "=v"(dx) : "v"(jx), "v"(nx));
    asm("v_pk_add_f32 %0, %1, %2" : "=v"(dy) : "v"(jy), "v"(ny));
    asm("v_pk_add_f32 %0, %1, %2" : "=v"(dz) : "v"(jz), "v"(nz));
    asm("v_pk_mul_f32 %0, %1, %1" : "=v"(t1) : "v"(dz));
    asm("v_pk_fma_f32 %0, %1, %1, %2" : "=v"(t2) : "v"(dy), "v"(t1));
    asm("v_pk_fma_f32 %0, %1, %1, %2" : "=v"(r2) : "v"(dx), "v"(t2));
    return r2;
}

// ---------------------------------------------------------------------------
// inner loop: per h-step, 2 uniform ds_read_b128 feed 2 j-atoms x IPT=4
// i-atoms = 8 pairs. LDS-pipe cost halved vs IPT=2 (R13 finding: LDS-bound).
// ---------------------------------------------------------------------------
template <bool SELFCHK>
__device__ __forceinline__ void tile_loop(const float4* __restrict__ A,
                                          const float4* __restrict__ B,
                                          int jbase,
                                          const int (&ii)[IPT],
                                          const f32x2 (&nX)[IPT],
                                          const f32x2 (&nY)[IPT],
                                          const f32x2 (&nZ)[IPT],
                                          float (&mm)[IPT],
                                          unsigned (&cA)[IPT], unsigned (&cB)[IPT]) {
#pragma unroll
    for (int h = 0; h < JT / 2; ++h) {
        const float4 a = A[h];                    // {x0,x1,y0,y1}
        const float4 b = B[h];                    // {z0,z1,s0bits,s1bits}
        const f32x2 jx = {a.x, a.y};
        const f32x2 jy = {a.z, a.w};
        const f32x2 jz = {b.x, b.y};
        const unsigned s0 = __float_as_uint(b.z);
        const unsigned s1 = __float_as_uint(b.w);
        const int j0 = jbase + 2 * h;
#pragma unroll
        for (int k = 0; k < IPT; ++k) {
            f32x2 r2 = pk_r2(jx, jy, jz, nX[k], nY[k], nZ[k]);
            float lo = r2.x, hi = r2.y;
            if (SELFCHK) {
                lo = (j0     == ii[k]) ? __builtin_inff() : lo;
                hi = (j0 + 1 == ii[k]) ? __builtin_inff() : hi;
            }
            mm[k] = fminf(mm[k], fminf(lo, hi));  // v_min3
            cA[k] += (lo < 36.0f) ? s0 : 0u;
            cB[k] += (hi < 36.0f) ? s1 : 0u;
        }
    }
}

// ---------------------------------------------------------------------------
// pair kernel: coalesced raw-stage of the 32-atom j-tile -> LDS assembly into
// pair-AoS {A,B}; each thread owns IPT=4 atoms (pre-negated coords). Writes
// partial {min_bits, packed_cnt}; no atomics. Block (0,0,0) zeroes out-tail.
// ---------------------------------------------------------------------------
__global__ __launch_bounds__(BLK) void ns_pair_kernel(const float* __restrict__ coord,
                                                      const int* __restrict__ atype,
                                                      uint2* __restrict__ part,
                                                      float* __restrict__ out,
                                                      int nloc) {
    const int f = blockIdx.z;
    const int q = nloc / IPT;                     // 1024
    const int ib = blockIdx.y * BLK;              // [0, q)
    const int jbase = blockIdx.x * JT;

    if (blockIdx.x == 0 && blockIdx.y == 0 && f == 0 && threadIdx.x < NFRAMES * NT)
        ((unsigned*)out)[(size_t)NFRAMES * nloc + threadIdx.x] = 0u;  // 0.0f bits

    const float* cf = coord + (size_t)f * nloc * 3;
    const int*   tf = atype + (size_t)f * nloc;

    __shared__ float    sraw[3 * JT];
    __shared__ unsigned ssv[JT];
    __shared__ float4   A[JT / 2], B[JT / 2];
    const int t = threadIdx.x;
    if (t < 3 * JT)
        sraw[t] = cf[3 * jbase + t];              // coalesced
    else if (t < 4 * JT)
        ssv[t - 3 * JT] = 1u << (tf[jbase + (t - 3 * JT)] * 8);
    __syncthreads();
    if (t < JT / 2)
        A[t] = make_float4(sraw[6 * t], sraw[6 * t + 3],
                           sraw[6 * t + 1], sraw[6 * t + 4]);
    else if (t < JT) {
        const int h = t - JT / 2;
        B[h] = make_float4(sraw[6 * h + 2], sraw[6 * h + 5],
                           __uint_as_float(ssv[2 * h]),
                           __uint_as_float(ssv[2 * h + 1]));
    }
    __syncthreads();

    int ii[IPT];
    f32x2 nX[IPT], nY[IPT], nZ[IPT];
    float mm[IPT];
    unsigned cA[IPT], cB[IPT];
    bool ov = false;
#pragma unroll
    for (int k = 0; k < IPT; ++k) {
        const int base = ib + k * q;
        ii[k] = base + t;
        const float nx = -cf[3 * ii[k]];
        const float ny = -cf[3 * ii[k] + 1];
        const float nz = -cf[3 * ii[k] + 2];
        nX[k] = (f32x2){nx, nx};
        nY[k] = (f32x2){ny, ny};
        nZ[k] = (f32x2){nz, nz};
        mm[k] = __builtin_inff();
        cA[k] = cB[k] = 0u;
        ov |= (jbase >= base) && (jbase < base + BLK);   // 32-tile inside 256-range
    }

    if (ov)
        tile_loop<true >(A, B, jbase, ii, nX, nY, nZ, mm, cA, cB);
    else
        tile_loop<false>(A, B, jbase, ii, nX, nY, nZ, mm, cA, cB);

    const size_t pb = ((size_t)blockIdx.x * NFRAMES + f) * nloc;
#pragma unroll
    for (int k = 0; k < IPT; ++k)
        part[pb + ii[k]] = make_uint2(__float_as_uint(mm[k]), cA[k] + cB[k]);
}

// ---------------------------------------------------------------------------
// finalize: one wave per 64 atoms; reduce NJ=128 partials per atom; write
// min_rr2; fold per-type count maxes into out tail via atomicMax on float bits
// ---------------------------------------------------------------------------
__global__ __launch_bounds__(FBLK) void ns_finalize_kernel(const uint2* __restrict__ part,
                                                           float* __restrict__ out,
                                                           int nloc) {
    const int nbpf = nloc / FBLK;                 // 64 blocks per frame
    const int f = blockIdx.x / nbpf;
    const int i = (blockIdx.x % nbpf) * FBLK + threadIdx.x;

    float ma = __builtin_inff(), mb = __builtin_inff();
    unsigned cacc = 0u, cbacc = 0u;
#pragma unroll 16
    for (int jb = 0; jb < NJ; jb += 2) {
        uint2 va = part[((size_t)jb * NFRAMES + f) * nloc + i];
        uint2 vb = part[((size_t)(jb + 1) * NFRAMES + f) * nloc + i];
        ma = fminf(ma, __uint_as_float(va.x));
        mb = fminf(mb, __uint_as_float(vb.x));
        cacc += va.y;
        cbacc += vb.y;
    }
    out[(size_t)f * nloc + i] = fminf(ma, mb);
    const unsigned c = cacc + cbacc;

    int m0 = (int)(c & 255u);
    int m1 = (int)((c >> 8) & 255u);
    int m2 = (int)((c >> 16) & 255u);
    int m3 = (int)(c >> 24);
    for (int off = 32; off > 0; off >>= 1) {
        m0 = max(m0, __shfl_xor(m0, off, 64));
        m1 = max(m1, __shfl_xor(m1, off, 64));
        m2 = max(m2, __shfl_xor(m2, off, 64));
        m3 = max(m3, __shfl_xor(m3, off, 64));
    }
    if (threadIdx.x < NT) {
        const int t = threadIdx.x;
        const int mv = (t == 0) ? m0 : (t == 1) ? m1 : (t == 2) ? m2 : m3;
        atomicMax((unsigned*)out + (size_t)NFRAMES * nloc + f * NT + t,
                  __float_as_uint((float)mv));
    }
}

extern "C" void kernel_launch(void* const* d_in, const int* in_sizes, int n_in,
                              void* d_out, int out_size, void* d_ws, size_t ws_size,
                              hipStream_t stream) {
    const float* coord = (const float*)d_in[0];
    const int*   atype = (const int*)d_in[1];
    const int nloc = in_sizes[1] / NFRAMES;

    float* out  = (float*)d_out;
    uint2* part = (uint2*)d_ws;                   // NJ * NFRAMES * nloc uint2 (8 MB)

    dim3 grid(NJ, nloc / (BLK * IPT), NFRAMES);
    ns_pair_kernel<<<grid, dim3(BLK), 0, stream>>>(coord, atype, part, out, nloc);

    const int nbpf = nloc / FBLK;
    ns_finalize_kernel<<<NFRAMES * nbpf, FBLK, 0, stream>>>(part, out, nloc);
}

// Round 15
// 25.289 us; speedup vs baseline: 7.0298x; 1.1968x over previous
//
#include <hip/hip_runtime.h>
#include <stdint.h>

#define NFRAMES 2
#define NT 4           // NTYPES
#define BLK 256        // pair-kernel block size (4 waves)
#define NJ 64          // j-chunks: nloc/NJ = 64 atoms per tile
#define JT 64          // j-tile size
#define IPT 4          // atoms per thread (each LDS read pair feeds 8 pairs)
#define FBLK 64        // finalize block size (1 wave)

typedef float f32x2 __attribute__((ext_vector_type(2)));

// ---------------------------------------------------------------------------
// 2 pairs via packed VOP3P f32 math (inline asm); i-coords pre-negated.
// ---------------------------------------------------------------------------
__device__ __forceinline__ f32x2 pk_r2(f32x2 jx, f32x2 jy, f32x2 jz,
                                       f32x2 nx, f32x2 ny, f32x2 nz) {
    f32x2 dx, dy, dz, t1, t2, r2;
    asm("v_pk_add_f32 %0, %1, %2" : "=v"(dx) : "v"(jx), "v"(nx));
    asm("v_pk_add_f32 %0, %1, %2" : "=v"(dy) : "v"(jy), "v"(ny));
    asm("v_pk_add_f32 %0, %1, %2" : "=v"(dz) : "v"(jz), "v"(nz));
    asm("v_pk_mul_f32 %0, %1, %1" : "=v"(t1) : "v"(dz));
    asm("v_pk_fma_f32 %0, %1, %1, %2" : "=v"(t2) : "v"(dy), "v"(t1));
    asm("v_pk_fma_f32 %0, %1, %1, %2" : "=v"(r2) : "v"(dx), "v"(t2));
    return r2;
}

// ---------------------------------------------------------------------------
// inner loop: per h-step, 2 uniform ds_read_b128 feed 2 j-atoms x IPT=4
// i-atoms = 8 pairs (R12 had 4). LDS reads/pair halved; 4x ILP per read.
// ---------------------------------------------------------------------------
template <bool SELFCHK>
__device__ __forceinline__ void tile_loop(const float4* __restrict__ A,
                                          const float4* __restrict__ B,
                                          int jbase,
                                          const int (&ii)[IPT],
                                          const f32x2 (&nX)[IPT],
                                          const f32x2 (&nY)[IPT],
                                          const f32x2 (&nZ)[IPT],
                                          float (&mm)[IPT],
                                          unsigned (&cA)[IPT], unsigned (&cB)[IPT]) {
#pragma unroll 8
    for (int h = 0; h < JT / 2; ++h) {
        const float4 a = A[h];                    // {x0,x1,y0,y1}
        const float4 b = B[h];                    // {z0,z1,s0bits,s1bits}
        const f32x2 jx = {a.x, a.y};
        const f32x2 jy = {a.z, a.w};
        const f32x2 jz = {b.x, b.y};
        const unsigned s0 = __float_as_uint(b.z);
        const unsigned s1 = __float_as_uint(b.w);
        const int j0 = jbase + 2 * h;
#pragma unroll
        for (int k = 0; k < IPT; ++k) {
            f32x2 r2 = pk_r2(jx, jy, jz, nX[k], nY[k], nZ[k]);
            float lo = r2.x, hi = r2.y;
            if (SELFCHK) {
                lo = (j0     == ii[k]) ? __builtin_inff() : lo;
                hi = (j0 + 1 == ii[k]) ? __builtin_inff() : hi;
            }
            mm[k] = fminf(mm[k], fminf(lo, hi));  // v_min3
            cA[k] += (lo < 36.0f) ? s0 : 0u;
            cB[k] += (hi < 36.0f) ? s1 : 0u;
        }
    }
}

// ---------------------------------------------------------------------------
// pair kernel: stage the 64-atom j-tile into pair-AoS LDS (A by lanes 0-31,
// B by lanes 32-63, one sync); each thread owns IPT=4 atoms (pre-negated).
// Writes partial {min_bits, packed_cnt}; no atomics. Block (0,0,0) zeroes
// the 8 output tail slots for finalize's atomicMax.
// ---------------------------------------------------------------------------
__global__ __launch_bounds__(BLK) void ns_pair_kernel(const float* __restrict__ coord,
                                                      const int* __restrict__ atype,
                                                      uint2* __restrict__ part,
                                                      float* __restrict__ out,
                                                      int nloc) {
    const int f = blockIdx.z;
    const int q = nloc / IPT;                     // 1024
    const int ib = blockIdx.y * BLK;              // [0, q)
    const int jbase = blockIdx.x * JT;

    if (blockIdx.x == 0 && blockIdx.y == 0 && f == 0 && threadIdx.x < NFRAMES * NT)
        ((unsigned*)out)[(size_t)NFRAMES * nloc + threadIdx.x] = 0u;  // 0.0f bits

    const float* cf = coord + (size_t)f * nloc * 3;
    const int*   tf = atype + (size_t)f * nloc;

    __shared__ float4 A[JT / 2], B[JT / 2];
    const int t = threadIdx.x;
    if (t < JT / 2) {
        const int j0 = jbase + 2 * t;
        A[t] = make_float4(cf[3 * j0], cf[3 * j0 + 3],
                           cf[3 * j0 + 1], cf[3 * j0 + 4]);
    } else if (t < JT) {
        const int h = t - JT / 2;
        const int j0 = jbase + 2 * h;
        B[h] = make_float4(cf[3 * j0 + 2], cf[3 * j0 + 5],
                           __uint_as_float(1u << (tf[j0] * 8)),
                           __uint_as_float(1u << (tf[j0 + 1] * 8)));
    }
    __syncthreads();

    int ii[IPT];
    f32x2 nX[IPT], nY[IPT], nZ[IPT];
    float mm[IPT];
    unsigned cA[IPT], cB[IPT];
    bool ov = false;
#pragma unroll
    for (int k = 0; k < IPT; ++k) {
        const int base = ib + k * q;
        ii[k] = base + t;
        const float nx = -cf[3 * ii[k]];
        const float ny = -cf[3 * ii[k] + 1];
        const float nz = -cf[3 * ii[k] + 2];
        nX[k] = (f32x2){nx, nx};
        nY[k] = (f32x2){ny, ny};
        nZ[k] = (f32x2){nz, nz};
        mm[k] = __builtin_inff();
        cA[k] = cB[k] = 0u;
        ov |= (jbase >= base) && (jbase < base + BLK);   // 64-tile inside 256-range
    }

    if (ov)
        tile_loop<true >(A, B, jbase, ii, nX, nY, nZ, mm, cA, cB);
    else
        tile_loop<false>(A, B, jbase, ii, nX, nY, nZ, mm, cA, cB);

    const size_t pb = ((size_t)blockIdx.x * NFRAMES + f) * nloc;
#pragma unroll
    for (int k = 0; k < IPT; ++k)
        part[pb + ii[k]] = make_uint2(__float_as_uint(mm[k]), cA[k] + cB[k]);
}

// ---------------------------------------------------------------------------
// finalize: one wave per 64 atoms; reduce NJ=64 partials per atom; write
// min_rr2; fold per-type count maxes into out tail via atomicMax on float bits
// (identical to R12).
// ---------------------------------------------------------------------------
__global__ __launch_bounds__(FBLK) void ns_finalize_kernel(const uint2* __restrict__ part,
                                                           float* __restrict__ out,
                                                           int nloc) {
    const int nbpf = nloc / FBLK;                 // 64 blocks per frame
    const int f = blockIdx.x / nbpf;
    const int i = (blockIdx.x % nbpf) * FBLK + threadIdx.x;

    float ma = __builtin_inff(), mb = __builtin_inff();
    unsigned cacc = 0u, cbacc = 0u;
#pragma unroll 16
    for (int jb = 0; jb < NJ; jb += 2) {
        uint2 va = part[((size_t)jb * NFRAMES + f) * nloc + i];
        uint2 vb = part[((size_t)(jb + 1) * NFRAMES + f) * nloc + i];
        ma = fminf(ma, __uint_as_float(va.x));
        mb = fminf(mb, __uint_as_float(vb.x));
        cacc += va.y;
        cbacc += vb.y;
    }
    out[(size_t)f * nloc + i] = fminf(ma, mb);
    const unsigned c = cacc + cbacc;

    int m0 = (int)(c & 255u);
    int m1 = (int)((c >> 8) & 255u);
    int m2 = (int)((c >> 16) & 255u);
    int m3 = (int)(c >> 24);
    for (int off = 32; off > 0; off >>= 1) {
        m0 = max(m0, __shfl_xor(m0, off, 64));
        m1 = max(m1, __shfl_xor(m1, off, 64));
        m2 = max(m2, __shfl_xor(m2, off, 64));
        m3 = max(m3, __shfl_xor(m3, off, 64));
    }
    if (threadIdx.x < NT) {
        const int t = threadIdx.x;
        const int mv = (t == 0) ? m0 : (t == 1) ? m1 : (t == 2) ? m2 : m3;
        atomicMax((unsigned*)out + (size_t)NFRAMES * nloc + f * NT + t,
                  __float_as_uint((float)mv));
    }
}

extern "C" void kernel_launch(void* const* d_in, const int* in_sizes, int n_in,
                              void* d_out, int out_size, void* d_ws, size_t ws_size,
                              hipStream_t stream) {
    const float* coord = (const float*)d_in[0];
    const int*   atype = (const int*)d_in[1];
    const int nloc = in_sizes[1] / NFRAMES;

    float* out  = (float*)d_out;
    uint2* part = (uint2*)d_ws;                   // NJ * NFRAMES * nloc uint2 (4 MB)

    dim3 grid(NJ, nloc / (BLK * IPT), NFRAMES);
    ns_pair_kernel<<<grid, dim3(BLK), 0, stream>>>(coord, atype, part, out, nloc);

    const int nbpf = nloc / FBLK;
    ns_finalize_kernel<<<NFRAMES * nbpf, FBLK, 0, stream>>>(part, out, nloc);
}

// Round 16
// 23.790 us; speedup vs baseline: 7.4730x; 1.0630x over previous
//
#include <hip/hip_runtime.h>
#include <stdint.h>

#define NFRAMES 2
#define NT 4           // NTYPES
#define BLK 256        // pair-kernel block size (4 waves)
#define NJ 64          // j-chunks: nloc/NJ = 64 atoms per tile
#define JT 64          // j-tile size (= nloc/NJ)
#define IPT 2          // atoms per thread in pair kernel
#define FBLK 64        // finalize block size (1 wave)

typedef float f32x2 __attribute__((ext_vector_type(2)));

// ---------------------------------------------------------------------------
// 2 pairs via packed VOP3P f32 math (inline asm); i-coords pre-negated.
// ---------------------------------------------------------------------------
__device__ __forceinline__ f32x2 pk_r2(f32x2 jx, f32x2 jy, f32x2 jz,
                                       f32x2 nx, f32x2 ny, f32x2 nz) {
    f32x2 dx, dy, dz, t1, t2, r2;
    asm("v_pk_add_f32 %0, %1, %2" : "=v"(dx) : "v"(jx), "v"(nx));
    asm("v_pk_add_f32 %0, %1, %2" : "=v"(dy) : "v"(jy), "v"(ny));
    asm("v_pk_add_f32 %0, %1, %2" : "=v"(dz) : "v"(jz), "v"(nz));
    asm("v_pk_mul_f32 %0, %1, %1" : "=v"(t1) : "v"(dz));
    asm("v_pk_fma_f32 %0, %1, %1, %2" : "=v"(t2) : "v"(dy), "v"(t1));
    asm("v_pk_fma_f32 %0, %1, %1, %2" : "=v"(r2) : "v"(dx), "v"(t2));
    return r2;
}

// ---------------------------------------------------------------------------
// inner loop over the LDS j-tile (pair-AoS): per h-step, 2 uniform
// ds_read_b128 feed 2 j-atoms x IPT i-atoms = 4 pairs of packed math.
// ---------------------------------------------------------------------------
template <bool SELFCHK>
__device__ __forceinline__ void tile_loop(const float4* __restrict__ A,
                                          const float4* __restrict__ B,
                                          int jbase,
                                          const int (&ii)[IPT],
                                          const f32x2 (&nX)[IPT],
                                          const f32x2 (&nY)[IPT],
                                          const f32x2 (&nZ)[IPT],
                                          float (&mm)[IPT],
                                          unsigned (&cA)[IPT], unsigned (&cB)[IPT]) {
#pragma unroll 8
    for (int h = 0; h < JT / 2; ++h) {
        const float4 a = A[h];                    // {x0,x1,y0,y1}
        const float4 b = B[h];                    // {z0,z1,s0bits,s1bits}
        const f32x2 jx = {a.x, a.y};
        const f32x2 jy = {a.z, a.w};
        const f32x2 jz = {b.x, b.y};
        const unsigned s0 = __float_as_uint(b.z);
        const unsigned s1 = __float_as_uint(b.w);
        const int j0 = jbase + 2 * h;
#pragma unroll
        for (int k = 0; k < IPT; ++k) {
            f32x2 r2 = pk_r2(jx, jy, jz, nX[k], nY[k], nZ[k]);
            float lo = r2.x, hi = r2.y;
            if (SELFCHK) {
                lo = (j0     == ii[k]) ? __builtin_inff() : lo;
                hi = (j0 + 1 == ii[k]) ? __builtin_inff() : hi;
            }
            mm[k] = fminf(mm[k], fminf(lo, hi));  // v_min3
            cA[k] += (lo < 36.0f) ? s0 : 0u;
            cB[k] += (hi < 36.0f) ? s1 : 0u;
        }
    }
}

// ---------------------------------------------------------------------------
// pair kernel (R12 + T14-style issue-early i-loads): i-coord global loads are
// issued BEFORE the LDS staging so their latency hides under staging + sync.
// ---------------------------------------------------------------------------
__global__ __launch_bounds__(BLK) void ns_pair_kernel(const float* __restrict__ coord,
                                                      const int* __restrict__ atype,
                                                      uint2* __restrict__ part,
                                                      float* __restrict__ out,
                                                      int nloc) {
    const int f = blockIdx.z;
    const int q = nloc / IPT;                     // 2048
    const int ib = blockIdx.y * BLK;              // [0, q)
    const int jbase = blockIdx.x * JT;

    if (blockIdx.x == 0 && blockIdx.y == 0 && f == 0 && threadIdx.x < NFRAMES * NT)
        ((unsigned*)out)[(size_t)NFRAMES * nloc + threadIdx.x] = 0u;  // 0.0f bits

    const float* cf = coord + (size_t)f * nloc * 3;
    const int*   tf = atype + (size_t)f * nloc;

    // ---- issue i-coord loads FIRST (latency hides under staging+sync) ----
    int ii[IPT];
    float lx[IPT], ly[IPT], lz[IPT];
    bool ov = false;
#pragma unroll
    for (int k = 0; k < IPT; ++k) {
        const int base = ib + k * q;
        ii[k] = base + threadIdx.x;
        lx[k] = cf[3 * ii[k]];
        ly[k] = cf[3 * ii[k] + 1];
        lz[k] = cf[3 * ii[k] + 2];
        ov |= (jbase >= base) && (jbase < base + BLK);   // 64-tile inside 256-range
    }

    // ---- stage j-tile into pair-AoS LDS ----
    __shared__ float4 A[JT / 2], B[JT / 2];
    if (threadIdx.x < JT / 2) {
        const int j0 = jbase + 2 * threadIdx.x;
        A[threadIdx.x] = make_float4(cf[3 * j0], cf[3 * j0 + 3],
                                     cf[3 * j0 + 1], cf[3 * j0 + 4]);
        B[threadIdx.x] = make_float4(cf[3 * j0 + 2], cf[3 * j0 + 5],
                                     __uint_as_float(1u << (tf[j0] * 8)),
                                     __uint_as_float(1u << (tf[j0 + 1] * 8)));
    }
    __syncthreads();

    f32x2 nX[IPT], nY[IPT], nZ[IPT];
    float mm[IPT];
    unsigned cA[IPT], cB[IPT];
#pragma unroll
    for (int k = 0; k < IPT; ++k) {
        const float nx = -lx[k], ny = -ly[k], nz = -lz[k];
        nX[k] = (f32x2){nx, nx};
        nY[k] = (f32x2){ny, ny};
        nZ[k] = (f32x2){nz, nz};
        mm[k] = __builtin_inff();
        cA[k] = cB[k] = 0u;
    }

    if (ov)
        tile_loop<true >(A, B, jbase, ii, nX, nY, nZ, mm, cA, cB);
    else
        tile_loop<false>(A, B, jbase, ii, nX, nY, nZ, mm, cA, cB);

    const size_t pb = ((size_t)blockIdx.x * NFRAMES + f) * nloc;
#pragma unroll
    for (int k = 0; k < IPT; ++k)
        part[pb + ii[k]] = make_uint2(__float_as_uint(mm[k]), cA[k] + cB[k]);
}

// ---------------------------------------------------------------------------
// finalize: one wave per 64 atoms; reduce NJ=64 partials per atom; write
// min_rr2; fold per-type count maxes into out tail via atomicMax on float bits
// (identical to R12).
// ---------------------------------------------------------------------------
__global__ __launch_bounds__(FBLK) void ns_finalize_kernel(const uint2* __restrict__ part,
                                                           float* __restrict__ out,
                                                           int nloc) {
    const int nbpf = nloc / FBLK;                 // 64 blocks per frame
    const int f = blockIdx.x / nbpf;
    const int i = (blockIdx.x % nbpf) * FBLK + threadIdx.x;

    float ma = __builtin_inff(), mb = __builtin_inff();
    unsigned cacc = 0u, cbacc = 0u;
#pragma unroll 16
    for (int jb = 0; jb < NJ; jb += 2) {
        uint2 va = part[((size_t)jb * NFRAMES + f) * nloc + i];
        uint2 vb = part[((size_t)(jb + 1) * NFRAMES + f) * nloc + i];
        ma = fminf(ma, __uint_as_float(va.x));
        mb = fminf(mb, __uint_as_float(vb.x));
        cacc += va.y;
        cbacc += vb.y;
    }
    out[(size_t)f * nloc + i] = fminf(ma, mb);
    const unsigned c = cacc + cbacc;

    int m0 = (int)(c & 255u);
    int m1 = (int)((c >> 8) & 255u);
    int m2 = (int)((c >> 16) & 255u);
    int m3 = (int)(c >> 24);
    for (int off = 32; off > 0; off >>= 1) {
        m0 = max(m0, __shfl_xor(m0, off, 64));
        m1 = max(m1, __shfl_xor(m1, off, 64));
        m2 = max(m2, __shfl_xor(m2, off, 64));
        m3 = max(m3, __shfl_xor(m3, off, 64));
    }
    if (threadIdx.x < NT) {
        const int t = threadIdx.x;
        const int mv = (t == 0) ? m0 : (t == 1) ? m1 : (t == 2) ? m2 : m3;
        atomicMax((unsigned*)out + (size_t)NFRAMES * nloc + f * NT + t,
                  __float_as_uint((float)mv));
    }
}

extern "C" void kernel_launch(void* const* d_in, const int* in_sizes, int n_in,
                              void* d_out, int out_size, void* d_ws, size_t ws_size,
                              hipStream_t stream) {
    const float* coord = (const float*)d_in[0];
    const int*   atype = (const int*)d_in[1];
    const int nloc = in_sizes[1] / NFRAMES;

    float* out  = (float*)d_out;
    uint2* part = (uint2*)d_ws;                   // NJ * NFRAMES * nloc uint2 (4 MB)

    dim3 grid(NJ, nloc / (BLK * IPT), NFRAMES);
    ns_pair_kernel<<<grid, dim3(BLK), 0, stream>>>(coord, atype, part, out, nloc);

    const int nbpf = nloc / FBLK;
    ns_finalize_kernel<<<NFRAMES * nbpf, FBLK, 0, stream>>>(part, out, nloc);
}